// Round 11
// baseline (124.414 us; speedup 1.0000x reference)
//
#include <hip/hip_runtime.h>

#define N_NODES 50000
#define N_EDGES 500000
#define NQ (N_EDGES / 4)   // 125000 edge quads
#define D 128
#define NBUCK 196          // bucket = dst >> 8 (256 nodes per bucket)
#define BN 256             // nodes per bucket
#define REG 4096           // record capacity per bucket (mean 2551, +30 sigma)
#define FXS 4194304.0f     // 2^22 fixed-point scale for weighted degree
#define AXS 2097152.0f     // 2^21 fixed-point scale for message sums (|sum| < 1024)

typedef unsigned long long u64;

// ---- prep: block 0 collapses weights (v = W1@(W2@Wf), c1, c0); block 1 zeros alloc.
__global__ void prep_kernel(const float* __restrict__ W1, const float* __restrict__ W2,
                            const float* __restrict__ b1, const float* __restrict__ b2,
                            const float* __restrict__ Wf, const float* __restrict__ bf,
                            float* __restrict__ v, float* __restrict__ consts,
                            unsigned* __restrict__ alloc) {
    const int t = threadIdx.x;
    if (blockIdx.x == 1) {
        if (t < 256) alloc[t] = 0u;
        return;
    }
    __shared__ float u[D];
    if (t < D) {
        float a = 0.f;
#pragma unroll 8
        for (int j = 0; j < D; ++j) a += W2[t * D + j] * Wf[j];
        u[t] = a;                                 // u = W2 @ Wf
    }
    __syncthreads();
    if (t < D) {
        float a = 0.f;
#pragma unroll 8
        for (int k = 0; k < D; ++k) a += W1[t * D + k] * u[k];
        v[t] = a;                                 // v = W1 @ u
    }
    if (t == 0) {
        float c = 0.f;
        for (int k = 0; k < D; ++k) c += b1[k] * u[k];
        consts[0] = c;                            // c1 = b1 . u
    } else if (t == 1) {
        float c = bf[0];
        for (int k = 0; k < D; ++k) c += b2[k] * Wf[k];
        consts[1] = c;                            // c0 = b2 . Wf + bf
    }
}

// ---- bucket: partition edges into 196 dst-range buckets of UNSORTED 8B records.
// Per block (4096 edges): LDS histogram -> one reserving global atomic per bucket
// (~24K total, vs 500K per-edge) -> scattered 8B record writes (runs of ~21).
// Record: hi = w bits, lo = (dst&255)<<16 | src
__global__ __launch_bounds__(512) void bucket_kernel(const int* __restrict__ src,
                                                     const int* __restrict__ dst,
                                                     const float* __restrict__ ew,
                                                     unsigned* __restrict__ alloc,
                                                     u64* __restrict__ recs) {
    __shared__ unsigned hist[NBUCK];
    const int t = threadIdx.x;
    if (t < NBUCK) hist[t] = 0u;
    __syncthreads();
    const int q0 = blockIdx.x * 1024 + t;
    const int q1 = q0 + 512;
    int4 dA, sA, dB, sB; float4 wA, wB;
    const bool aA = q0 < NQ, aB = q1 < NQ;
    if (aA) {
        dA = ((const int4*)dst)[q0]; sA = ((const int4*)src)[q0]; wA = ((const float4*)ew)[q0];
        atomicAdd(&hist[dA.x >> 8], 1u); atomicAdd(&hist[dA.y >> 8], 1u);
        atomicAdd(&hist[dA.z >> 8], 1u); atomicAdd(&hist[dA.w >> 8], 1u);
    }
    if (aB) {
        dB = ((const int4*)dst)[q1]; sB = ((const int4*)src)[q1]; wB = ((const float4*)ew)[q1];
        atomicAdd(&hist[dB.x >> 8], 1u); atomicAdd(&hist[dB.y >> 8], 1u);
        atomicAdd(&hist[dB.z >> 8], 1u); atomicAdd(&hist[dB.w >> 8], 1u);
    }
    __syncthreads();
    if (t < NBUCK) hist[t] = atomicAdd(&alloc[t], hist[t]);   // run base -> block cursor
    __syncthreads();
#define PLACE(dd, ss, ww)                                                        \
    {   int bkt = (dd) >> 8;                                                     \
        unsigned p = atomicAdd(&hist[bkt], 1u);                                  \
        if (p < REG)                                                             \
            recs[(size_t)bkt * REG + p] =                                        \
                ((u64)__float_as_uint(ww) << 32) |                               \
                ((unsigned)((dd) & 255) << 16) | (unsigned)(ss);                 \
    }
    if (aA) { PLACE(dA.x, sA.x, wA.x) PLACE(dA.y, sA.y, wA.y)
              PLACE(dA.z, sA.z, wA.z) PLACE(dA.w, sA.w, wA.w) }
    if (aB) { PLACE(dB.x, sB.x, wB.x) PLACE(dB.y, sB.y, wB.y)
              PLACE(dB.z, sB.z, wB.z) PLACE(dB.w, sB.w, wB.w) }
#undef PLACE
}

// ---- fused degtw+gemv: one block per bucket.
// Phase 1: stream records -> fixed-point weighted degree in LDS.
// Phase 2: gemv for the bucket's own 256 nodes (block-contiguous 128 KB x-read),
//          emit dinv[n] = rsqrt(deg+1), tw[n] = dinv[n] * (x[n,:].v).
__global__ __launch_bounds__(512) void degtw_kernel(const u64* __restrict__ recs,
                                                    const unsigned* __restrict__ alloc,
                                                    const float* __restrict__ x,
                                                    const float* __restrict__ v,
                                                    float* __restrict__ dinv,
                                                    float* __restrict__ tw) {
    __shared__ float vs[D];
    __shared__ unsigned ws[BN];
    const int b = blockIdx.x, t = threadIdx.x;
    if (t < D) vs[t] = v[t];
    if (t < BN) ws[t] = 0u;
    __syncthreads();
    unsigned total = alloc[b];
    if (total > REG) total = REG;
    const u64* rb = recs + (size_t)b * REG;
    for (unsigned i = t; i < total; i += 512) {
        u64 r = rb[i];
        float w = __uint_as_float((unsigned)(r >> 32));
        atomicAdd(&ws[((unsigned)r >> 16) & 0xffu], __float2uint_rn(w * FXS));
    }
    __syncthreads();
    const int l = t & 31;
    const int sub = t >> 5;                       // 16 node-groups of 32 lanes
#pragma unroll
    for (int k = 0; k < BN / 16; ++k) {           // 16 iterations cover 256 nodes
        int ln = k * 16 + sub;
        int n = b * BN + ln;
        if (n < N_NODES) {
            float4 xv = ((const float4*)(x + (size_t)n * D))[l];
            float a = xv.x * vs[l * 4] + xv.y * vs[l * 4 + 1] +
                      xv.z * vs[l * 4 + 2] + xv.w * vs[l * 4 + 3];
#pragma unroll
            for (int off = 16; off > 0; off >>= 1) a += __shfl_xor(a, off);
            if (l == 0) {
                float di = rsqrtf((float)ws[ln] * (1.0f / FXS) + 1.0f);
                dinv[n] = di;
                tw[n] = di * a;
            }
        }
    }
}

// ---- gather_s: one block per bucket. acc[d] += w*tw[src] in s32 fixed point (LDS),
// then sw[n] = di*( di*(acc + tw[n]) + c1 ).
__global__ __launch_bounds__(512) void gather_s_kernel(const u64* __restrict__ recs,
                                                       const unsigned* __restrict__ alloc,
                                                       const float* __restrict__ tw,
                                                       const float* __restrict__ dinv,
                                                       const float* __restrict__ consts,
                                                       float* __restrict__ sw) {
    __shared__ int acc[BN];
    const int b = blockIdx.x, t = threadIdx.x;
    if (t < BN) acc[t] = 0;
    __syncthreads();
    unsigned total = alloc[b];
    if (total > REG) total = REG;
    const u64* rb = recs + (size_t)b * REG;
    for (unsigned i = t; i < total; i += 512) {
        u64 r = rb[i];
        unsigned lo = (unsigned)r;
        float m = __uint_as_float((unsigned)(r >> 32)) * tw[lo & 0xffffu];
        atomicAdd(&acc[(lo >> 16) & 0xffu], __float2int_rn(m * AXS));
    }
    __syncthreads();
    if (t < BN) {
        int n = b * BN + t;
        if (n < N_NODES) {
            float di = dinv[n];
            float a = (float)acc[t] * (1.0f / AXS);
            sw[n] = di * (di * (a + tw[n]) + consts[0]);
        }
    }
}

// ---- gather_z: same shape; out[n] = sigmoid( di*(acc + sw[n]) + c0 ) * 10.
__global__ __launch_bounds__(512) void gather_z_kernel(const u64* __restrict__ recs,
                                                       const unsigned* __restrict__ alloc,
                                                       const float* __restrict__ sw,
                                                       const float* __restrict__ dinv,
                                                       const float* __restrict__ consts,
                                                       float* __restrict__ out) {
    __shared__ int acc[BN];
    const int b = blockIdx.x, t = threadIdx.x;
    if (t < BN) acc[t] = 0;
    __syncthreads();
    unsigned total = alloc[b];
    if (total > REG) total = REG;
    const u64* rb = recs + (size_t)b * REG;
    for (unsigned i = t; i < total; i += 512) {
        u64 r = rb[i];
        unsigned lo = (unsigned)r;
        float m = __uint_as_float((unsigned)(r >> 32)) * sw[lo & 0xffffu];
        atomicAdd(&acc[(lo >> 16) & 0xffu], __float2int_rn(m * AXS));
    }
    __syncthreads();
    if (t < BN) {
        int n = b * BN + t;
        if (n < N_NODES) {
            float di = dinv[n];
            float a = (float)acc[t] * (1.0f / AXS);
            float z = di * (a + sw[n]) + consts[1];
            out[n] = 10.0f / (1.0f + expf(-z));
        }
    }
}

extern "C" void kernel_launch(void* const* d_in, const int* in_sizes, int n_in,
                              void* d_out, int out_size, void* d_ws, size_t ws_size,
                              hipStream_t stream) {
    const float* x  = (const float*)d_in[0];
    const int*   ei = (const int*)d_in[1];
    const float* ew = (const float*)d_in[2];
    const float* W1 = (const float*)d_in[3];
    const float* b1 = (const float*)d_in[4];
    const float* W2 = (const float*)d_in[5];
    const float* b2 = (const float*)d_in[6];
    const float* Wf = (const float*)d_in[7];
    const float* bf = (const float*)d_in[8];
    const int* srcv = ei;
    const int* dstv = ei + N_EDGES;
    float* out = (float*)d_out;

    char* p = (char*)d_ws;
    auto alloc_ws = [&](size_t bytes) { void* r = (void*)p; p += (bytes + 255) & ~(size_t)255; return r; };
    unsigned* alloc  = (unsigned*)alloc_ws(256 * 4);
    u64*      recs   = (u64*)alloc_ws((size_t)NBUCK * REG * 8);   // 6.4 MB
    float*    dinv   = (float*)alloc_ws(N_NODES * 4);
    float*    tw     = (float*)alloc_ws(N_NODES * 4);
    float*    sw     = (float*)alloc_ws(N_NODES * 4);
    float*    v      = (float*)alloc_ws(D * 4);
    float*    consts = (float*)alloc_ws(2 * 4);

    const int BB = (NQ + 1023) / 1024;    // 123 bucket blocks (4096 edges each)

    // weight collapse + zero bucket allocators (no memset dispatch)
    prep_kernel<<<2, 256, 0, stream>>>(W1, W2, b1, b2, Wf, bf, v, consts, alloc);

    // partition edges into 196 unsorted bucket regions (no per-node sort)
    bucket_kernel<<<BB, 512, 0, stream>>>(srcv, dstv, ew, alloc, recs);

    // fused: per-bucket degree accumulation + gemv -> dinv, tw  (was 2 dispatches)
    degtw_kernel<<<NBUCK, 512, 0, stream>>>(recs, alloc, x, v, dinv, tw);

    // the two layers, per-bucket LDS accumulation
    gather_s_kernel<<<NBUCK, 512, 0, stream>>>(recs, alloc, tw, dinv, consts, sw);
    gather_z_kernel<<<NBUCK, 512, 0, stream>>>(recs, alloc, sw, dinv, consts, out);
}

// Round 12
// 120.572 us; speedup vs baseline: 1.0319x; 1.0319x over previous
//
#include <hip/hip_runtime.h>

#define N_NODES 50000
#define N_EDGES 500000
#define NQ (N_EDGES / 4)   // 125000 edge quads
#define D 128
#define NBUCK 196          // bucket = dst >> 8 (256 nodes per bucket)
#define BN 256             // nodes per bucket
#define NBLK 123           // bucket-writer blocks (4096 edges each)
#define CELL 64            // records per (block,bucket) cell; mean 20.9, P(>63)~1e-8
#define GEMVB 3125         // gemv blocks in mid kernel (16 nodes x 512 thr each)
#define FXS 4194304.0f     // 2^22 fixed-point scale for weighted degree
#define AXS 2097152.0f     // 2^21 fixed-point scale for message sums

typedef unsigned long long u64;

// ---- D1: bucket build, atomic-free (private cells). Block NBLK does weight collapse.
// Record: hi = w bits, lo = (dst&255)<<16 | src   (src < 2^16 since N_NODES = 50000)
__global__ __launch_bounds__(512) void build_kernel(const int* __restrict__ src,
                                                    const int* __restrict__ dst,
                                                    const float* __restrict__ ew,
                                                    const float* __restrict__ W1,
                                                    const float* __restrict__ W2,
                                                    const float* __restrict__ b1,
                                                    const float* __restrict__ b2,
                                                    const float* __restrict__ Wf,
                                                    const float* __restrict__ bf,
                                                    u64* __restrict__ recs,
                                                    unsigned* __restrict__ cnts,
                                                    float* __restrict__ v,
                                                    float* __restrict__ consts) {
    const int t = threadIdx.x;
    const int blk = blockIdx.x;
    if (blk == NBLK) {                            // weight collapse (v, c1, c0)
        __shared__ float u[D];
        if (t < D) {
            float a = 0.f;
#pragma unroll 8
            for (int j = 0; j < D; ++j) a += W2[t * D + j] * Wf[j];
            u[t] = a;                             // u = W2 @ Wf
        }
        __syncthreads();
        if (t < D) {
            float a = 0.f;
#pragma unroll 8
            for (int k = 0; k < D; ++k) a += W1[t * D + k] * u[k];
            v[t] = a;                             // v = W1 @ u
        }
        if (t == 0) {
            float c = 0.f;
            for (int k = 0; k < D; ++k) c += b1[k] * u[k];
            consts[0] = c;                        // c1 = b1 . u
        } else if (t == 1) {
            float c = bf[0];
            for (int k = 0; k < D; ++k) c += b2[k] * Wf[k];
            consts[1] = c;                        // c0 = b2 . Wf + bf
        }
        return;
    }
    __shared__ unsigned cur[NBUCK];
    if (t < NBUCK) cur[t] = 0u;
    __syncthreads();
    const int q0 = blk * 1024 + t;
    const int q1 = q0 + 512;
#define PLACE(dd, ss, ww)                                                         \
    {   int bkt = (dd) >> 8;                                                      \
        unsigned slot = atomicAdd(&cur[bkt], 1u);                                 \
        if (slot < CELL)                                                          \
            recs[((size_t)bkt * NBLK + blk) * CELL + slot] =                      \
                ((u64)__float_as_uint(ww) << 32) |                                \
                ((unsigned)((dd) & 255) << 16) | (unsigned)(ss);                  \
    }
    if (q0 < NQ) {
        int4 d4 = ((const int4*)dst)[q0];
        int4 s4 = ((const int4*)src)[q0];
        float4 w4 = ((const float4*)ew)[q0];
        PLACE(d4.x, s4.x, w4.x) PLACE(d4.y, s4.y, w4.y)
        PLACE(d4.z, s4.z, w4.z) PLACE(d4.w, s4.w, w4.w)
    }
    if (q1 < NQ) {
        int4 d4 = ((const int4*)dst)[q1];
        int4 s4 = ((const int4*)src)[q1];
        float4 w4 = ((const float4*)ew)[q1];
        PLACE(d4.x, s4.x, w4.x) PLACE(d4.y, s4.y, w4.y)
        PLACE(d4.z, s4.z, w4.z) PLACE(d4.w, s4.w, w4.w)
    }
#undef PLACE
    __syncthreads();
    if (t < NBUCK) {
        unsigned c = cur[t];
        cnts[(size_t)t * NBLK + blk] = (c < CELL) ? c : CELL;
    }
}

// ---- D2: block-specialized mid kernel.
// blocks [0, GEMVB): traw[n] = x[n,:].v   (full-grid BW stream, 16 nodes/block)
// blocks [GEMVB, GEMVB+NBUCK): per-bucket weighted degree -> dinv[n]
__global__ __launch_bounds__(512) void mid_kernel(const float* __restrict__ x,
                                                  const float* __restrict__ v,
                                                  const u64* __restrict__ recs,
                                                  const unsigned* __restrict__ cnts,
                                                  float* __restrict__ traw,
                                                  float* __restrict__ dinv) {
    const int t = threadIdx.x;
    const int bid = blockIdx.x;
    if (bid < GEMVB) {
        __shared__ float vs[D];
        if (t < D) vs[t] = v[t];
        __syncthreads();
        const int l = t & 31;
        const int n = bid * 16 + (t >> 5);        // 3125*16 = 50000, exact
        float4 xv = ((const float4*)(x + (size_t)n * D))[l];
        float a = xv.x * vs[l * 4] + xv.y * vs[l * 4 + 1] +
                  xv.z * vs[l * 4 + 2] + xv.w * vs[l * 4 + 3];
#pragma unroll
        for (int off = 16; off > 0; off >>= 1) a += __shfl_xor(a, off);
        if (l == 0) traw[n] = a;
        return;
    }
    const int b = bid - GEMVB;
    __shared__ unsigned ws[BN];
    __shared__ unsigned cl[NBLK];
    if (t < BN) ws[t] = 0u;
    if (t < NBLK) cl[t] = cnts[(size_t)b * NBLK + t];
    __syncthreads();
    const int wid = t >> 6, lane = t & 63;
    for (int c = wid; c < NBLK; c += 8) {
        if (lane < (int)cl[c]) {
            u64 r = recs[((size_t)b * NBLK + c) * CELL + lane];
            float w = __uint_as_float((unsigned)(r >> 32));
            atomicAdd(&ws[((unsigned)r >> 16) & 0xffu], __float2uint_rn(w * FXS));
        }
    }
    __syncthreads();
    if (t < BN) {
        int n = b * BN + t;
        if (n < N_NODES)
            dinv[n] = rsqrtf((float)ws[t] * (1.0f / FXS) + 1.0f);
    }
}

// ---- D3: gather_s. acc[d] += w * dinv[src]*traw[src]  (s32 fixed point in LDS);
// sw[n] = di*( di*(acc + di*traw[n]) + c1 )
__global__ __launch_bounds__(512) void gather_s_kernel(const u64* __restrict__ recs,
                                                       const unsigned* __restrict__ cnts,
                                                       const float* __restrict__ traw,
                                                       const float* __restrict__ dinv,
                                                       const float* __restrict__ consts,
                                                       float* __restrict__ sw) {
    const int b = blockIdx.x, t = threadIdx.x;
    __shared__ int acc[BN];
    __shared__ unsigned cl[NBLK];
    if (t < BN) acc[t] = 0;
    if (t < NBLK) cl[t] = cnts[(size_t)b * NBLK + t];
    __syncthreads();
    const int wid = t >> 6, lane = t & 63;
    for (int c = wid; c < NBLK; c += 8) {
        if (lane < (int)cl[c]) {
            u64 r = recs[((size_t)b * NBLK + c) * CELL + lane];
            unsigned lo = (unsigned)r;
            int s = lo & 0xffff;
            float m = __uint_as_float((unsigned)(r >> 32)) * dinv[s] * traw[s];
            atomicAdd(&acc[(lo >> 16) & 0xffu], __float2int_rn(m * AXS));
        }
    }
    __syncthreads();
    if (t < BN) {
        int n = b * BN + t;
        if (n < N_NODES) {
            float di = dinv[n];
            float twn = di * traw[n];
            float a = (float)acc[t] * (1.0f / AXS);
            sw[n] = di * (di * (a + twn) + consts[0]);
        }
    }
}

// ---- D4: gather_z. acc[d] += w*sw[src]; out[n] = sigmoid( di*(acc + sw[n]) + c0 )*10
__global__ __launch_bounds__(512) void gather_z_kernel(const u64* __restrict__ recs,
                                                       const unsigned* __restrict__ cnts,
                                                       const float* __restrict__ sw,
                                                       const float* __restrict__ dinv,
                                                       const float* __restrict__ consts,
                                                       float* __restrict__ out) {
    const int b = blockIdx.x, t = threadIdx.x;
    __shared__ int acc[BN];
    __shared__ unsigned cl[NBLK];
    if (t < BN) acc[t] = 0;
    if (t < NBLK) cl[t] = cnts[(size_t)b * NBLK + t];
    __syncthreads();
    const int wid = t >> 6, lane = t & 63;
    for (int c = wid; c < NBLK; c += 8) {
        if (lane < (int)cl[c]) {
            u64 r = recs[((size_t)b * NBLK + c) * CELL + lane];
            unsigned lo = (unsigned)r;
            float m = __uint_as_float((unsigned)(r >> 32)) * sw[lo & 0xffffu];
            atomicAdd(&acc[(lo >> 16) & 0xffu], __float2int_rn(m * AXS));
        }
    }
    __syncthreads();
    if (t < BN) {
        int n = b * BN + t;
        if (n < N_NODES) {
            float di = dinv[n];
            float a = (float)acc[t] * (1.0f / AXS);
            float z = di * (a + sw[n]) + consts[1];
            out[n] = 10.0f / (1.0f + expf(-z));
        }
    }
}

extern "C" void kernel_launch(void* const* d_in, const int* in_sizes, int n_in,
                              void* d_out, int out_size, void* d_ws, size_t ws_size,
                              hipStream_t stream) {
    const float* x  = (const float*)d_in[0];
    const int*   ei = (const int*)d_in[1];
    const float* ew = (const float*)d_in[2];
    const float* W1 = (const float*)d_in[3];
    const float* b1 = (const float*)d_in[4];
    const float* W2 = (const float*)d_in[5];
    const float* b2 = (const float*)d_in[6];
    const float* Wf = (const float*)d_in[7];
    const float* bf = (const float*)d_in[8];
    const int* srcv = ei;
    const int* dstv = ei + N_EDGES;
    float* out = (float*)d_out;

    char* p = (char*)d_ws;
    auto alloc_ws = [&](size_t bytes) { void* r = (void*)p; p += (bytes + 255) & ~(size_t)255; return r; };
    u64*      recs   = (u64*)alloc_ws((size_t)NBUCK * NBLK * CELL * 8);  // 12.3 MB
    unsigned* cnts   = (unsigned*)alloc_ws((size_t)NBUCK * NBLK * 4);    // 96 KB
    float*    traw   = (float*)alloc_ws(N_NODES * 4);
    float*    dinv   = (float*)alloc_ws(N_NODES * 4);
    float*    sw     = (float*)alloc_ws(N_NODES * 4);
    float*    v      = (float*)alloc_ws(D * 4);
    float*    consts = (float*)alloc_ws(2 * 4);

    // D1: atomic-free bucket build + weight collapse (no memset, no prep dispatch)
    build_kernel<<<NBLK + 1, 512, 0, stream>>>(srcv, dstv, ew, W1, W2, b1, b2, Wf, bf,
                                               recs, cnts, v, consts);

    // D2: gemv (full-grid) | per-bucket degree -> dinv   (block-specialized)
    mid_kernel<<<GEMVB + NBUCK, 512, 0, stream>>>(x, v, recs, cnts, traw, dinv);

    // D3, D4: the two aggregation layers
    gather_s_kernel<<<NBUCK, 512, 0, stream>>>(recs, cnts, traw, dinv, consts, sw);
    gather_z_kernel<<<NBUCK, 512, 0, stream>>>(recs, cnts, sw, dinv, consts, out);
}

// Round 13
// 114.332 us; speedup vs baseline: 1.0882x; 1.0546x over previous
//
#include <hip/hip_runtime.h>

#define N_NODES 50000
#define N_EDGES 500000
#define NQ (N_EDGES / 4)   // 125000 edge quads
#define D 128
#define NBUCK 196          // bucket = dst >> 8 (256 nodes per bucket)
#define BN 256             // nodes per bucket
#define REG 4096           // record capacity per bucket (mean 2551, +30 sigma)
#define GEMVB 3125         // gemv blocks in mid kernel (16 nodes x 512 thr each)
#define FXS 4194304.0f     // 2^22 fixed-point scale for weighted degree
#define AXS 2097152.0f     // 2^21 fixed-point scale for message sums (|sum| < 1024)

typedef unsigned long long u64;

// ---- D1: bucket build (R10's proven compact version) + weight collapse in the
// extra block. Per writer block (4096 edges): LDS histogram -> one reserving
// global atomic per bucket (~24K total) -> scattered 8B records (runs of ~21).
// Record: hi = w bits, lo = (dst&255)<<16 | src    (src < 2^16: N_NODES = 50000)
__global__ __launch_bounds__(512) void bucket_kernel(const int* __restrict__ src,
                                                     const int* __restrict__ dst,
                                                     const float* __restrict__ ew,
                                                     const float* __restrict__ W1,
                                                     const float* __restrict__ W2,
                                                     const float* __restrict__ b1,
                                                     const float* __restrict__ b2,
                                                     const float* __restrict__ Wf,
                                                     const float* __restrict__ bf,
                                                     unsigned* __restrict__ alloc,
                                                     u64* __restrict__ recs,
                                                     float* __restrict__ v,
                                                     float* __restrict__ consts,
                                                     int nwb) {
    const int t = threadIdx.x;
    if ((int)blockIdx.x == nwb) {                 // weight collapse (v, c1, c0)
        __shared__ float u[D];
        if (t < D) {
            float a = 0.f;
#pragma unroll 8
            for (int j = 0; j < D; ++j) a += W2[t * D + j] * Wf[j];
            u[t] = a;                             // u = W2 @ Wf
        }
        __syncthreads();
        if (t < D) {
            float a = 0.f;
#pragma unroll 8
            for (int k = 0; k < D; ++k) a += W1[t * D + k] * u[k];
            v[t] = a;                             // v = W1 @ u
        }
        if (t == 0) {
            float c = 0.f;
            for (int k = 0; k < D; ++k) c += b1[k] * u[k];
            consts[0] = c;                        // c1 = b1 . u
        } else if (t == 1) {
            float c = bf[0];
            for (int k = 0; k < D; ++k) c += b2[k] * Wf[k];
            consts[1] = c;                        // c0 = b2 . Wf + bf
        }
        return;
    }
    __shared__ unsigned hist[NBUCK];
    if (t < NBUCK) hist[t] = 0u;
    __syncthreads();
    const int q0 = blockIdx.x * 1024 + t;
    const int q1 = q0 + 512;
    int4 dA, sA, dB, sB; float4 wA, wB;
    const bool aA = q0 < NQ, aB = q1 < NQ;
    if (aA) {
        dA = ((const int4*)dst)[q0]; sA = ((const int4*)src)[q0]; wA = ((const float4*)ew)[q0];
        atomicAdd(&hist[dA.x >> 8], 1u); atomicAdd(&hist[dA.y >> 8], 1u);
        atomicAdd(&hist[dA.z >> 8], 1u); atomicAdd(&hist[dA.w >> 8], 1u);
    }
    if (aB) {
        dB = ((const int4*)dst)[q1]; sB = ((const int4*)src)[q1]; wB = ((const float4*)ew)[q1];
        atomicAdd(&hist[dB.x >> 8], 1u); atomicAdd(&hist[dB.y >> 8], 1u);
        atomicAdd(&hist[dB.z >> 8], 1u); atomicAdd(&hist[dB.w >> 8], 1u);
    }
    __syncthreads();
    if (t < NBUCK) hist[t] = atomicAdd(&alloc[t], hist[t]);   // run base -> cursor
    __syncthreads();
#define PLACE(dd, ss, ww)                                                        \
    {   int bkt = (dd) >> 8;                                                     \
        unsigned p = atomicAdd(&hist[bkt], 1u);                                  \
        if (p < REG)                                                             \
            recs[(size_t)bkt * REG + p] =                                        \
                ((u64)__float_as_uint(ww) << 32) |                               \
                ((unsigned)((dd) & 255) << 16) | (unsigned)(ss);                 \
    }
    if (aA) { PLACE(dA.x, sA.x, wA.x) PLACE(dA.y, sA.y, wA.y)
              PLACE(dA.z, sA.z, wA.z) PLACE(dA.w, sA.w, wA.w) }
    if (aB) { PLACE(dB.x, sB.x, wB.x) PLACE(dB.y, sB.y, wB.y)
              PLACE(dB.z, sB.z, wB.z) PLACE(dB.w, sB.w, wB.w) }
#undef PLACE
}

// ---- D2: block-specialized mid kernel (shapes preserved from R10/R12 winners).
// blocks [0, GEMVB): traw[n] = x[n,:].v   (full-grid BW stream, 16 nodes/block)
// blocks [GEMVB, GEMVB+NBUCK): per-bucket weighted degree from COMPACT records
//                              (all-lane streaming loop) -> dinv[n]
__global__ __launch_bounds__(512) void mid_kernel(const float* __restrict__ x,
                                                  const float* __restrict__ v,
                                                  const u64* __restrict__ recs,
                                                  const unsigned* __restrict__ alloc,
                                                  float* __restrict__ traw,
                                                  float* __restrict__ dinv) {
    const int t = threadIdx.x;
    const int bid = blockIdx.x;
    if (bid < GEMVB) {
        __shared__ float vs[D];
        if (t < D) vs[t] = v[t];
        __syncthreads();
        const int l = t & 31;
        const int n = bid * 16 + (t >> 5);        // 3125*16 = 50000, exact
        float4 xv = ((const float4*)(x + (size_t)n * D))[l];
        float a = xv.x * vs[l * 4] + xv.y * vs[l * 4 + 1] +
                  xv.z * vs[l * 4 + 2] + xv.w * vs[l * 4 + 3];
#pragma unroll
        for (int off = 16; off > 0; off >>= 1) a += __shfl_xor(a, off);
        if (l == 0) traw[n] = a;
        return;
    }
    const int b = bid - GEMVB;
    __shared__ unsigned ws[BN];
    if (t < BN) ws[t] = 0u;
    __syncthreads();
    unsigned total = alloc[b];
    if (total > REG) total = REG;
    const u64* rb = recs + (size_t)b * REG;
    for (unsigned i = t; i < total; i += 512) {   // all 512 lanes active
        u64 r = rb[i];
        float w = __uint_as_float((unsigned)(r >> 32));
        atomicAdd(&ws[((unsigned)r >> 16) & 0xffu], __float2uint_rn(w * FXS));
    }
    __syncthreads();
    if (t < BN) {
        int n = b * BN + t;
        if (n < N_NODES)
            dinv[n] = rsqrtf((float)ws[t] * (1.0f / FXS) + 1.0f);
    }
}

// ---- D3: gather_s. acc[d] += w * (dinv[src]*traw[src]) in s32 fixed point (LDS);
// sw[n] = di*( di*(acc + di*traw[n]) + c1 ).  dinv/traw are L2-resident 200 KB.
__global__ __launch_bounds__(512) void gather_s_kernel(const u64* __restrict__ recs,
                                                       const unsigned* __restrict__ alloc,
                                                       const float* __restrict__ traw,
                                                       const float* __restrict__ dinv,
                                                       const float* __restrict__ consts,
                                                       float* __restrict__ sw) {
    __shared__ int acc[BN];
    const int b = blockIdx.x, t = threadIdx.x;
    if (t < BN) acc[t] = 0;
    __syncthreads();
    unsigned total = alloc[b];
    if (total > REG) total = REG;
    const u64* rb = recs + (size_t)b * REG;
    for (unsigned i = t; i < total; i += 512) {
        u64 r = rb[i];
        unsigned lo = (unsigned)r;
        int s = lo & 0xffff;
        float m = __uint_as_float((unsigned)(r >> 32)) * dinv[s] * traw[s];
        atomicAdd(&acc[(lo >> 16) & 0xffu], __float2int_rn(m * AXS));
    }
    __syncthreads();
    if (t < BN) {
        int n = b * BN + t;
        if (n < N_NODES) {
            float di = dinv[n];
            float twn = di * traw[n];
            float a = (float)acc[t] * (1.0f / AXS);
            sw[n] = di * (di * (a + twn) + consts[0]);
        }
    }
}

// ---- D4: gather_z. acc[d] += w*sw[src]; out[n] = sigmoid( di*(acc+sw[n]) + c0 )*10
__global__ __launch_bounds__(512) void gather_z_kernel(const u64* __restrict__ recs,
                                                       const unsigned* __restrict__ alloc,
                                                       const float* __restrict__ sw,
                                                       const float* __restrict__ dinv,
                                                       const float* __restrict__ consts,
                                                       float* __restrict__ out) {
    __shared__ int acc[BN];
    const int b = blockIdx.x, t = threadIdx.x;
    if (t < BN) acc[t] = 0;
    __syncthreads();
    unsigned total = alloc[b];
    if (total > REG) total = REG;
    const u64* rb = recs + (size_t)b * REG;
    for (unsigned i = t; i < total; i += 512) {
        u64 r = rb[i];
        unsigned lo = (unsigned)r;
        float m = __uint_as_float((unsigned)(r >> 32)) * sw[lo & 0xffffu];
        atomicAdd(&acc[(lo >> 16) & 0xffu], __float2int_rn(m * AXS));
    }
    __syncthreads();
    if (t < BN) {
        int n = b * BN + t;
        if (n < N_NODES) {
            float di = dinv[n];
            float a = (float)acc[t] * (1.0f / AXS);
            float z = di * (a + sw[n]) + consts[1];
            out[n] = 10.0f / (1.0f + expf(-z));
        }
    }
}

extern "C" void kernel_launch(void* const* d_in, const int* in_sizes, int n_in,
                              void* d_out, int out_size, void* d_ws, size_t ws_size,
                              hipStream_t stream) {
    const float* x  = (const float*)d_in[0];
    const int*   ei = (const int*)d_in[1];
    const float* ew = (const float*)d_in[2];
    const float* W1 = (const float*)d_in[3];
    const float* b1 = (const float*)d_in[4];
    const float* W2 = (const float*)d_in[5];
    const float* b2 = (const float*)d_in[6];
    const float* Wf = (const float*)d_in[7];
    const float* bf = (const float*)d_in[8];
    const int* srcv = ei;
    const int* dstv = ei + N_EDGES;
    float* out = (float*)d_out;

    char* p = (char*)d_ws;
    auto alloc_ws = [&](size_t bytes) { void* r = (void*)p; p += (bytes + 255) & ~(size_t)255; return r; };
    unsigned* alloc  = (unsigned*)alloc_ws(256 * 4);
    u64*      recs   = (u64*)alloc_ws((size_t)NBUCK * REG * 8);   // 6.4 MB compact
    float*    traw   = (float*)alloc_ws(N_NODES * 4);
    float*    dinv   = (float*)alloc_ws(N_NODES * 4);
    float*    sw     = (float*)alloc_ws(N_NODES * 4);
    float*    v      = (float*)alloc_ws(D * 4);
    float*    consts = (float*)alloc_ws(2 * 4);

    const int NWB = (NQ + 1023) / 1024;   // 123 writer blocks

    // tiny 784B zero of the bucket allocators (replaces the prep dispatch)
    hipMemsetAsync(alloc, 0, NBUCK * 4, stream);

    // D1: compact bucket build + weight collapse (extra block)
    bucket_kernel<<<NWB + 1, 512, 0, stream>>>(srcv, dstv, ew, W1, W2, b1, b2, Wf, bf,
                                               alloc, recs, v, consts, NWB);

    // D2: gemv (full grid) | per-bucket degree (compact stream) -> traw, dinv
    mid_kernel<<<GEMVB + NBUCK, 512, 0, stream>>>(x, v, recs, alloc, traw, dinv);

    // D3, D4: the two aggregation layers (compact all-lane streams)
    gather_s_kernel<<<NBUCK, 512, 0, stream>>>(recs, alloc, traw, dinv, consts, sw);
    gather_z_kernel<<<NBUCK, 512, 0, stream>>>(recs, alloc, sw, dinv, consts, out);
}